// Round 3
// baseline (487.040 us; speedup 1.0000x reference)
//
#include <hip/hip_runtime.h>
#include <hip/hip_bf16.h>

// Bahdanau attention, MI355X. B=64 S=1024 E=1024 D=512.
// Score GEMM: M = B*S = 65536, K = E = 1024, N = D = 512 (full N per block).
// Fused flash-style epilogue: block-local masked softmax partials + partial
// context; per-batch combine kernel finishes softmax + context exactly.

typedef __attribute__((ext_vector_type(4))) float f32x4;
typedef __attribute__((ext_vector_type(2))) float f32x2;
typedef __attribute__((ext_vector_type(8))) short short8;
typedef __attribute__((ext_vector_type(8))) __bf16 bf16x8;

__device__ __forceinline__ void gload_lds16(const void* g, void* l) {
  __builtin_amdgcn_global_load_lds(
      (const __attribute__((address_space(1))) unsigned int*)g,
      (__attribute__((address_space(3))) unsigned int*)l,
      16, 0, 0);
}

__device__ __forceinline__ unsigned short f2bf_rne(float f) {
  union { float f; unsigned int u; } v; v.f = f;
  unsigned int r = v.u + 0x7FFFu + ((v.u >> 16) & 1u);
  return (unsigned short)(r >> 16);
}

__device__ __forceinline__ float fast_tanh(float x) {
  float e = __expf(2.0f * x);                      // inf-safe: e=inf -> 1, e=0 -> -1
  return 1.0f - 2.0f * __builtin_amdgcn_rcpf(e + 1.0f);
}

// ---- h_proj: hb[b][d] = sum_k hidden[b][k] * attn_W[k][d]
__global__ void hproj_kernel(const float* __restrict__ hidden,
                             const float* __restrict__ attn_W,
                             float* __restrict__ hb /* zeroed */) {
  int b = blockIdx.x >> 2, kc = blockIdx.x & 3;
  int tid = threadIdx.x;
  __shared__ float hrow[128];
  if (tid < 128) hrow[tid] = hidden[b * 512 + kc * 128 + tid];
  __syncthreads();
  const float* Wp = attn_W + (size_t)(kc * 128) * 512;
  float a0 = 0.f, a1 = 0.f;
#pragma unroll 4
  for (int k = 0; k < 128; ++k) {
    float h = hrow[k];
    a0 = fmaf(h, Wp[(size_t)k * 512 + tid], a0);
    a1 = fmaf(h, Wp[(size_t)k * 512 + tid + 256], a1);
  }
  atomicAdd(&hb[b * 512 + tid], a0);
  atomicAdd(&hb[b * 512 + tid + 256], a1);
}

// ---- W_e transpose+convert: weT[d][e] = bf16(attn_W[512+e][d]),  [512][1024] bf16
__global__ void wet_kernel(const float* __restrict__ attn_W,
                           unsigned short* __restrict__ weT) {
  __shared__ float tile[64][65];
  int bx = blockIdx.x;
  int kt = bx & 15;          // e-tile (16)
  int nt = bx >> 4;          // d-tile (8)
  int tid = threadIdx.x;
  int j = tid & 63, i = tid >> 6;
  const float* src = attn_W + (size_t)(512 + kt * 64) * 512 + nt * 64;
#pragma unroll
  for (int p = 0; p < 16; ++p) {
    int r = p * 4 + i;
    tile[r][j] = src[(size_t)r * 512 + j];
  }
  __syncthreads();
  unsigned short* dst = weT + (size_t)(nt * 64) * 1024 + kt * 64;
#pragma unroll
  for (int p = 0; p < 16; ++p) {
    int c = p * 4 + i;
    dst[(size_t)c * 1024 + j] = f2bf_rne(tile[j][c]);
  }
}

// ---- fused: e_proj GEMM (BM=128, BN=512 full, BK=64) + tanh + dot(v) ->
//      block-local masked softmax partial + partial context.
// 8 waves (512 thr) as 2m x 4n; per-wave output 64x128; acc 128 VGPR.
__global__ __launch_bounds__(512, 2) void fused_score_ctx(
    const float* __restrict__ enc,            // [65536][1024] fp32 (A)
    const unsigned short* __restrict__ weT,   // [512][1024] bf16  (B rows = N)
    const float* __restrict__ hb,             // [64][512]
    const float* __restrict__ attn_b,         // [512]
    const float* __restrict__ vW,             // [512]
    const int* __restrict__ mask,             // [64][1024]
    float* __restrict__ scores,               // [65536] masked scores
    float* __restrict__ pmax,                 // [512] per-strip max
    float* __restrict__ psum,                 // [512] per-strip sum(exp)
    float* __restrict__ pctx)                 // [512][1024] partial context
{
  __shared__ unsigned short At[128 * 64];     // 16 KB, XOR-swizzled 16B slots
  __shared__ unsigned short Bt[512 * 64];     // 64 KB, XOR-swizzled 16B slots
  __shared__ float sc[4][128];                // per-n-wave row partials
  __shared__ float parr[128];                 // exp(score - m_i)
  __shared__ float redm[2], reds[2];

  const float NEG = -3.402823466e38f;
  int bx = blockIdx.x;
  int strip = ((bx & 7) << 6) | (bx >> 3);    // XCD swizzle (512 % 8 == 0)
  int m0 = strip << 7;
  int b = m0 >> 10;

  int tid = threadIdx.x;
  int w = tid >> 6, l = tid & 63;
  int g = l >> 4, l15 = l & 15;
  int wm = w >> 2, wn = w & 3;                // 2m x 4n

  // ---- A staging map: thread owns 16 consecutive floats of row (tid>>2)
  int arow = tid >> 2;
  int as0 = (tid & 3) << 1;                   // 16B-slot pair {as0, as0+1}
  const float* Ap = enc + (size_t)(m0 + arow) * 1024 + (as0 << 3);
  int awb0 = arow * 128 + ((as0 ^ (arow & 7)) << 4);
  int awb1 = arow * 128 + (((as0 + 1) ^ (arow & 7)) << 4);

  // ---- B staging (gload_lds, 8 rounds): chunk c = i*512 + tid
  int brow0 = tid >> 3;                       // + i*64
  int bs = (tid & 7) ^ (brow0 & 7);           // i-invariant (i*64 % 8 == 0)
  const unsigned short* Bp = weT + (size_t)brow0 * 1024 + (bs << 3);

  f32x4 zero = {0.f, 0.f, 0.f, 0.f};
  f32x4 acc[4][8];
#pragma unroll
  for (int i = 0; i < 4; ++i)
#pragma unroll
    for (int j = 0; j < 8; ++j) acc[i][j] = zero;

  // ---- LDS read byte offsets (kk=0); kk=1 via XOR 64 (slot-bit2 <-> byte 64)
  int aRd[4], bRd[8];
#pragma unroll
  for (int mt = 0; mt < 4; ++mt) {
    int row = wm * 64 + mt * 16 + l15;
    aRd[mt] = row * 128 + ((g ^ (row & 7)) << 4);
  }
#pragma unroll
  for (int nt = 0; nt < 8; ++nt) {
    int row = wn * 128 + nt * 16 + l15;
    bRd[nt] = row * 128 + ((g ^ (row & 7)) << 4);
  }

  const char* Atc = (const char*)At;
  const char* Btc = (const char*)Bt;

  // prologue: A(kt=0) into regs
  f32x4 rA0 = *(const f32x4*)(Ap + 0);
  f32x4 rA1 = *(const f32x4*)(Ap + 4);
  f32x4 rA2 = *(const f32x4*)(Ap + 8);
  f32x4 rA3 = *(const f32x4*)(Ap + 12);

  for (int kt = 0; kt < 16; ++kt) {
    int k0n = (kt + (kt < 15)) << 6;          // next k (clamped; redundant last)
    __syncthreads();                          // prev-tile readers done
    // stage A: cvt fp32->bf16, 2x ds_write_b128 (swizzled dest)
    {
      bf16x8 v0, v1;
      v0[0] = (__bf16)rA0[0]; v0[1] = (__bf16)rA0[1];
      v0[2] = (__bf16)rA0[2]; v0[3] = (__bf16)rA0[3];
      v0[4] = (__bf16)rA1[0]; v0[5] = (__bf16)rA1[1];
      v0[6] = (__bf16)rA1[2]; v0[7] = (__bf16)rA1[3];
      v1[0] = (__bf16)rA2[0]; v1[1] = (__bf16)rA2[1];
      v1[2] = (__bf16)rA2[2]; v1[3] = (__bf16)rA2[3];
      v1[4] = (__bf16)rA3[0]; v1[5] = (__bf16)rA3[1];
      v1[6] = (__bf16)rA3[2]; v1[7] = (__bf16)rA3[3];
      *(short8*)((char*)At + awb0) = __builtin_bit_cast(short8, v0);
      *(short8*)((char*)At + awb1) = __builtin_bit_cast(short8, v1);
    }
    // stage B: 8 async rounds (swizzled source, linear dest)
#pragma unroll
    for (int i = 0; i < 8; ++i)
      gload_lds16(Bp + (i << 16) + (kt << 6),
                  (char*)Bt + (i << 13) + (w << 10));
    __syncthreads();                          // vmcnt+lgkm drained before barrier
    // prefetch next A tile into regs (overlaps compute)
    rA0 = *(const f32x4*)(Ap + k0n + 0);
    rA1 = *(const f32x4*)(Ap + k0n + 4);
    rA2 = *(const f32x4*)(Ap + k0n + 8);
    rA3 = *(const f32x4*)(Ap + k0n + 12);
    // compute
#pragma unroll
    for (int kk = 0; kk < 2; ++kk) {
      int kx = kk << 6;
      short8 af[4], bfm[8];
#pragma unroll
      for (int mt = 0; mt < 4; ++mt)
        af[mt] = *(const short8*)(Atc + (aRd[mt] ^ kx));
#pragma unroll
      for (int nt = 0; nt < 8; ++nt)
        bfm[nt] = *(const short8*)(Btc + (bRd[nt] ^ kx));
#pragma unroll
      for (int mt = 0; mt < 4; ++mt)
#pragma unroll
        for (int nt = 0; nt < 8; ++nt)
          acc[mt][nt] = __builtin_amdgcn_mfma_f32_16x16x32_bf16(
              af[mt], bfm[nt], acc[mt][nt], 0, 0, 0);
    }
  }

  // ---- per-wave score partials: sum_d tanh(acc + hb + bias) * v over 128 cols
  float hbv[8], vwv[8];
#pragma unroll
  for (int nt = 0; nt < 8; ++nt) {
    int d = wn * 128 + nt * 16 + l15;
    hbv[nt] = hb[(b << 9) + d] + attn_b[d];
    vwv[nt] = vW[d];
  }
#pragma unroll
  for (int mt = 0; mt < 4; ++mt) {
#pragma unroll
    for (int j = 0; j < 4; ++j) {
      float p = 0.f;
#pragma unroll
      for (int nt = 0; nt < 8; ++nt)
        p = fmaf(fast_tanh(acc[mt][nt][j] + hbv[nt]), vwv[nt], p);
      p += __shfl_xor(p, 1);
      p += __shfl_xor(p, 2);
      p += __shfl_xor(p, 4);
      p += __shfl_xor(p, 8);
      if (l15 == 0)
        sc[wn][wm * 64 + mt * 16 + (g << 2) + j] = p;
    }
  }
  __syncthreads();

  // ---- block softmax partial over the 128 rows (threads 0..127 = 2 waves)
  float s4 = 0.f;
  if (tid < 128) {
    s4 = sc[0][tid] + sc[1][tid] + sc[2][tid] + sc[3][tid];
    int gm = m0 + tid;
    if (mask[gm] == 0) s4 = NEG;
    scores[gm] = s4;
    float mx = s4;
#pragma unroll
    for (int off = 1; off < 64; off <<= 1) mx = fmaxf(mx, __shfl_xor(mx, off));
    if (l == 0) redm[w] = mx;
  }
  __syncthreads();
  if (tid < 128) {
    float M_i = fmaxf(redm[0], redm[1]);
    float pex = __expf(s4 - M_i);             // NEG-NEG == 0 -> 1 (all-masked ok)
    parr[tid] = pex;
    float sm = pex;
#pragma unroll
    for (int off = 1; off < 64; off <<= 1) sm += __shfl_xor(sm, off);
    if (l == 0) reds[w] = sm;
  }
  __syncthreads();
  if (tid == 0) {
    pmax[strip] = fmaxf(redm[0], redm[1]);
    psum[strip] = reds[0] + reds[1];
  }

  // ---- partial context: pctx[strip][e] = sum_s parr[s] * enc[m0+s][e]
  float c0 = 0.f, c1 = 0.f;
  const float* ep = enc + (size_t)m0 * 1024 + (tid << 1);
#pragma unroll 4
  for (int s = 0; s < 128; ++s) {
    float ps = parr[s];
    f32x2 v = *(const f32x2*)(ep + ((size_t)s << 10));
    c0 = fmaf(ps, v[0], c0);
    c1 = fmaf(ps, v[1], c1);
  }
  float* pc = pctx + ((size_t)strip << 10) + (tid << 1);
  pc[0] = c0; pc[1] = c1;
}

// ---- combine: finish softmax + context per batch
__global__ void combine_kernel(const float* __restrict__ scores,
                               const float* __restrict__ pmax,
                               const float* __restrict__ psum,
                               const float* __restrict__ pctx,
                               float* __restrict__ out) {
  int b = blockIdx.x, tid = threadIdx.x;      // 64 blocks x 256 thr
  float m8[8];
  float M = pmax[b * 8];
  m8[0] = M;
#pragma unroll
  for (int i = 1; i < 8; ++i) { m8[i] = pmax[b * 8 + i]; M = fmaxf(M, m8[i]); }
  float e8[8]; float L = 0.f;
#pragma unroll
  for (int i = 0; i < 8; ++i) {
    e8[i] = __expf(m8[i] - M);
    L = fmaf(e8[i], psum[b * 8 + i], L);
  }
  float invL = 1.f / L;
  // context: 1024 e, f32x4 per thread
  f32x4 a = {0.f, 0.f, 0.f, 0.f};
#pragma unroll
  for (int i = 0; i < 8; ++i) {
    f32x4 v = *(const f32x4*)(pctx + (size_t)(b * 8 + i) * 1024 + (tid << 2));
#pragma unroll
    for (int j = 0; j < 4; ++j) a[j] = fmaf(e8[i], v[j], a[j]);
  }
#pragma unroll
  for (int j = 0; j < 4; ++j) a[j] *= invL;
  *(f32x4*)(out + (b << 10) + (tid << 2)) = a;
  // weights: exp(score - M) / L
  f32x4 sv = *(const f32x4*)(scores + (b << 10) + (tid << 2));
  f32x4 wv;
#pragma unroll
  for (int j = 0; j < 4; ++j) wv[j] = __expf(sv[j] - M) * invL;
  *(f32x4*)(out + 65536 + (b << 10) + (tid << 2)) = wv;
}

extern "C" void kernel_launch(void* const* d_in, const int* in_sizes, int n_in,
                              void* d_out, int out_size, void* d_ws, size_t ws_size,
                              hipStream_t stream) {
  const float* hidden = (const float*)d_in[0];
  const float* enc    = (const float*)d_in[1];
  const int*   mask   = (const int*)d_in[2];
  const float* attn_W = (const float*)d_in[3];
  const float* attn_b = (const float*)d_in[4];
  const float* vW     = (const float*)d_in[5];
  float* out = (float*)d_out;   // [0,65536): context ; [65536,131072): attn_weights

  float* scores = (float*)d_ws;                        // 65536 f32
  float* hb     = scores + 65536;                      // 32768 f32
  unsigned short* weT = (unsigned short*)(hb + 32768); // 524288 bf16 (1 MB)
  float* pmax = (float*)(weT + 524288);                // 512 f32
  float* psum = pmax + 512;                            // 512 f32
  float* pctx = psum + 512;                            // 512*1024 f32 (2 MB)

  hipMemsetAsync(hb, 0, 32768 * sizeof(float), stream);   // hb only (atomics)

  hproj_kernel<<<256, 256, 0, stream>>>(hidden, attn_W, hb);
  wet_kernel<<<128, 256, 0, stream>>>(attn_W, weT);
  fused_score_ctx<<<512, 512, 0, stream>>>(enc, weT, hb, attn_b, vW, mask,
                                           scores, pmax, psum, pctx);
  combine_kernel<<<64, 256, 0, stream>>>(scores, pmax, psum, pctx, out);
}